// Round 2
// baseline (3701.860 us; speedup 1.0000x reference)
//
#include <hip/hip_runtime.h>

using short8  = __attribute__((ext_vector_type(8))) short;
using half8   = __attribute__((ext_vector_type(8))) _Float16;
using f32x16  = __attribute__((ext_vector_type(16))) float;
using float4v = __attribute__((ext_vector_type(4))) float;

#define T_STEPS 256
#define BATCH   512
#define HID     2048
#define KS      128   // HID/16 k-steps
// Fragment order for packed operands: ((blk32*KS + ks)*64 + lane) * 16B
// lane l: row/col = blk32*32 + (l&31), k = ks*16 + (l>>5)*8 + e (e=0..7 contiguous)
// (exact per-lane k permutation is irrelevant as long as A and B use the same map)

__device__ __forceinline__ f32x16 zero16() {
  f32x16 z;
#pragma unroll
  for (int r = 0; r < 16; ++r) z[r] = 0.0f;
  return z;
}

// ---- packing kernels ----
__global__ void pack_whh_k(const float* __restrict__ whh, half8* __restrict__ bp) {
  int id   = blockIdx.x * 256 + threadIdx.x;   // [0, 64*128*64)
  int lane = id & 63;
  int ks   = (id >> 6) & 127;
  int nblk = id >> 13;
  int j = nblk * 32 + (lane & 31);
  int k = ks * 16 + (lane >> 5) * 8;
  const float4v* src = (const float4v*)(whh + (size_t)j * HID + k);
  float4v a = src[0], b = src[1];
  half8 v;
  v[0]=(_Float16)a[0]; v[1]=(_Float16)a[1]; v[2]=(_Float16)a[2]; v[3]=(_Float16)a[3];
  v[4]=(_Float16)b[0]; v[5]=(_Float16)b[1]; v[6]=(_Float16)b[2]; v[7]=(_Float16)b[3];
  bp[id] = v;
}

__global__ void pack_h_k(const float* __restrict__ hsrc, half8* __restrict__ hp) {
  int id   = blockIdx.x * 256 + threadIdx.x;   // [0, 16*128*64)
  int lane = id & 63;
  int ks   = (id >> 6) & 127;
  int bblk = id >> 13;
  int b = bblk * 32 + (lane & 31);
  int k = ks * 16 + (lane >> 5) * 8;
  const float4v* src = (const float4v*)(hsrc + (size_t)b * HID + k);
  float4v a = src[0], c = src[1];
  half8 v;
  v[0]=(_Float16)a[0]; v[1]=(_Float16)a[1]; v[2]=(_Float16)a[2]; v[3]=(_Float16)a[3];
  v[4]=(_Float16)c[0]; v[5]=(_Float16)c[1]; v[6]=(_Float16)c[2]; v[7]=(_Float16)c[3];
  hp[id] = v;
}

__global__ void bias_k(const float* __restrict__ bih, const float* __restrict__ bhh,
                       float* __restrict__ bias) {
  int i = blockIdx.x * 256 + threadIdx.x;
  if (i < HID) bias[i] = bih[i] + bhh[i];
}

__global__ void outinit_k(float* __restrict__ out, const float* __restrict__ bout) {
  int i = blockIdx.x * 256 + threadIdx.x;      // grid covers T*B exactly
  out[i] = bout[0];
}

// Canonicalize tf_mask (unknown storage: int64 0/1, int32 0/1, or 1-byte bool) -> int[256].
__global__ void tf_expand_k(const int* __restrict__ tf, int* __restrict__ tfc) {
  __shared__ int fmt;   // 0=bytes, 1=int32, 2=int64
  if (threadIdx.x == 0) {
    const unsigned* u = (const unsigned*)tf;
    int all01 = 1;
    for (int i = 0; i < 32; ++i) if (u[i] > 1u) all01 = 0;
    if (all01) {
      int odd0 = 1;
      for (int i = 1; i < 32; i += 2) if (u[i] != 0u) odd0 = 0;
      fmt = odd0 ? 2 : 1;   // all odd words zero -> int64
    } else {
      fmt = 0;              // bytes with values beyond {0,1} in word view -> bool bytes
    }
  }
  __syncthreads();
  int i = threadIdx.x;
  int v;
  if (fmt == 2)      v = tf[2 * i];
  else if (fmt == 1) v = tf[i];
  else               v = (int)((const unsigned char*)tf)[i];
  tfc[i] = v ? 1 : 0;
}

// ---- one recurrence step ----
// grid 256 blocks x 256 thr. bid = m*32 + n  (n = bid&31 -> XCD = n%8 for L2 locality:
// each XCD caches only its 1MB slice of W_hh + the 2MB h buffer).
// Block (m,n): batch rows m*64..+64, hidden cols n*64..+64. Wave w = k-quarter.
__global__ __launch_bounds__(256) void step_k(
    const float* __restrict__ x0,   const float* __restrict__ tgt,
    const int*   __restrict__ tfc,  const float* __restrict__ wih,
    const float* __restrict__ wout, const float* __restrict__ bias,
    const half8* __restrict__ wp,   const half8* __restrict__ hr,
    half8* __restrict__ hw,         float* __restrict__ out, int t) {
  __shared__ float part[4][64][68];   // k-quarter partial pre-activations
  __shared__ float hs[64][68];        // tanh'd h tile (f32)
  __shared__ float xs[64];
  __shared__ float ypart[4][64];
  __shared__ float wih_s[64], wout_s[64], bias_s[64];

  const int bid = blockIdx.x;
  const int n = bid & 31;
  const int m = bid >> 5;
  const int tid = threadIdx.x;
  const int w = tid >> 6;     // wave = k-quarter
  const int l = tid & 63;
  const int hi = l >> 5;
  const int c = l & 31;

  if (tid < 64) {
    int j = n * 64 + tid;
    wih_s[tid]  = wih[j];
    wout_s[tid] = wout[j];
    bias_s[tid] = bias[j];
    int b = m * 64 + tid;
    float x;
    if (t == 0) x = x0[b];
    else        x = tfc[t - 1] ? tgt[(t - 1) * BATCH + b] : out[(t - 1) * BATCH + b];
    xs[tid] = x;
  }

  f32x16 acc00 = zero16(), acc01 = zero16(), acc10 = zero16(), acc11 = zero16();
  {
    const half8* a0p = hr + ((size_t)(2 * m + 0) * KS + w * 32) * 64 + l;
    const half8* a1p = hr + ((size_t)(2 * m + 1) * KS + w * 32) * 64 + l;
    const half8* b0p = wp + ((size_t)(2 * n + 0) * KS + w * 32) * 64 + l;
    const half8* b1p = wp + ((size_t)(2 * n + 1) * KS + w * 32) * 64 + l;
#pragma unroll
    for (int i = 0; i < 32; ++i) {
      half8 a0 = a0p[i * 64];
      half8 a1 = a1p[i * 64];
      half8 b0 = b0p[i * 64];
      half8 b1 = b1p[i * 64];
      acc00 = __builtin_amdgcn_mfma_f32_32x32x16_f16(a0, b0, acc00, 0, 0, 0);
      acc01 = __builtin_amdgcn_mfma_f32_32x32x16_f16(a0, b1, acc01, 0, 0, 0);
      acc10 = __builtin_amdgcn_mfma_f32_32x32x16_f16(a1, b0, acc10, 0, 0, 0);
      acc11 = __builtin_amdgcn_mfma_f32_32x32x16_f16(a1, b1, acc11, 0, 0, 0);
    }
  }

  // C/D layout (m74/m101): col = lane&31, row = (reg&3) + 8*(reg>>2) + 4*(lane>>5)
#pragma unroll
  for (int r = 0; r < 16; ++r) {
    int row0 = (r & 3) + 8 * (r >> 2) + 4 * hi;
    part[w][row0     ][c     ] = acc00[r];
    part[w][row0     ][c + 32] = acc01[r];
    part[w][row0 + 32][c     ] = acc10[r];
    part[w][row0 + 32][c + 32] = acc11[r];
  }
  __syncthreads();

  // combine k-quarters (wave -> quadrant), add rank-1 input term + bias, tanh
  {
    int mb = w & 1, nb = w >> 1;
#pragma unroll
    for (int r = 0; r < 16; ++r) {
      int row = mb * 32 + (r & 3) + 8 * (r >> 2) + 4 * hi;
      int col = nb * 32 + c;
      float s = part[0][row][col] + part[1][row][col]
              + part[2][row][col] + part[3][row][col];
      s += bias_s[col] + xs[row] * wih_s[col];
      hs[row][col] = tanhf(s);
    }
  }
  __syncthreads();

  // repack h_t to A-fragment layout (fp16) + per-wave y partials
  {
    int row = tid & 63;
    int ksl = tid >> 6;
    float hv[16];
#pragma unroll
    for (int q = 0; q < 4; ++q) {
      float4v v = *(const float4v*)&hs[row][ksl * 16 + q * 4];
      hv[q * 4 + 0] = v[0]; hv[q * 4 + 1] = v[1];
      hv[q * 4 + 2] = v[2]; hv[q * 4 + 3] = v[3];
    }
    float yp = 0.0f;
#pragma unroll
    for (int e = 0; e < 16; ++e) yp += hv[e] * wout_s[ksl * 16 + e];
    ypart[ksl][row] = yp;

    half8 f0, f1;
#pragma unroll
    for (int e = 0; e < 8; ++e) { f0[e] = (_Float16)hv[e]; f1[e] = (_Float16)hv[8 + e]; }
    int bblk = 2 * m + (row >> 5);
    int ksg  = n * 4 + ksl;
    size_t base = ((size_t)bblk * KS + ksg) * 64;
    hw[base + (row & 31)     ] = f0;
    hw[base + (row & 31) + 32] = f1;
  }
  __syncthreads();

  if (tid < 64) {
    float y = ypart[0][tid] + ypart[1][tid] + ypart[2][tid] + ypart[3][tid];
    atomicAdd(out + (size_t)t * BATCH + m * 64 + tid, y);
  }
}

extern "C" void kernel_launch(void* const* d_in, const int* in_sizes, int n_in,
                              void* d_out, int out_size, void* d_ws, size_t ws_size,
                              hipStream_t stream) {
  (void)in_sizes; (void)n_in; (void)out_size; (void)ws_size;
  const float* x0   = (const float*)d_in[0];
  const float* hid  = (const float*)d_in[1];
  const float* tgt  = (const float*)d_in[2];
  const float* wih  = (const float*)d_in[3];
  const float* bih  = (const float*)d_in[4];
  const float* whh  = (const float*)d_in[5];
  const float* bhh  = (const float*)d_in[6];
  const float* wout = (const float*)d_in[7];
  const float* bout = (const float*)d_in[8];
  const int*   tf   = (const int*)d_in[9];
  float* out = (float*)d_out;

  char* ws = (char*)d_ws;
  half8* wp   = (half8*)ws;                        // 8 MB packed W_hh fp16
  half8* h0   = (half8*)(ws + (8u  << 20));        // 2 MB packed h (ping)
  half8* h1   = (half8*)(ws + (10u << 20));        // 2 MB packed h (pong)
  float* bias = (float*)(ws + (12u << 20));        // 8 KB b_ih + b_hh
  int*   tfc  = (int*)  (ws + (12u << 20) + 8192); // 1 KB canonical tf

  pack_whh_k <<<2048, 256, 0, stream>>>(whh, wp);
  pack_h_k   <<<512,  256, 0, stream>>>(hid, h0);
  bias_k     <<<8,    256, 0, stream>>>(bih, bhh, bias);
  outinit_k  <<<512,  256, 0, stream>>>(out, bout);
  tf_expand_k<<<1,    256, 0, stream>>>(tf, tfc);

  for (int t = 0; t < T_STEPS; ++t) {
    const half8* hr = (t & 1) ? h1 : h0;
    half8*       hv = (t & 1) ? h0 : h1;
    step_k<<<256, 256, 0, stream>>>(x0, tgt, tfc, wih, wout, bias, wp, hr, hv, out, t);
  }
}

// Round 3
// 2892.907 us; speedup vs baseline: 1.2796x; 1.2796x over previous
//
#include <hip/hip_runtime.h>

using half8   = __attribute__((ext_vector_type(8))) _Float16;
using f32x16  = __attribute__((ext_vector_type(16))) float;
using float4v = __attribute__((ext_vector_type(4))) float;

#define T_STEPS 256
#define BATCH   512
#define HID     2048
#define KS      128   // HID/16 k-steps
// Fragment order for packed operands: ((blk32*KS + ks)*64 + lane) * 16B
// lane l: row/col = blk32*32 + (l&31), k = ks*16 + (l>>5)*8 + e (e=0..7 contiguous)

__device__ __forceinline__ f32x16 zero16() {
  f32x16 z;
#pragma unroll
  for (int r = 0; r < 16; ++r) z[r] = 0.0f;
  return z;
}

// ---- packing kernels ----
__global__ void pack_whh_k(const float* __restrict__ whh, half8* __restrict__ bp) {
  int id   = blockIdx.x * 256 + threadIdx.x;   // [0, 64*128*64)
  int lane = id & 63;
  int ks   = (id >> 6) & 127;
  int nblk = id >> 13;
  int j = nblk * 32 + (lane & 31);
  int k = ks * 16 + (lane >> 5) * 8;
  const float4v* src = (const float4v*)(whh + (size_t)j * HID + k);
  float4v a = src[0], b = src[1];
  half8 v;
  v[0]=(_Float16)a[0]; v[1]=(_Float16)a[1]; v[2]=(_Float16)a[2]; v[3]=(_Float16)a[3];
  v[4]=(_Float16)b[0]; v[5]=(_Float16)b[1]; v[6]=(_Float16)b[2]; v[7]=(_Float16)b[3];
  bp[id] = v;
}

__global__ void pack_h_k(const float* __restrict__ hsrc, half8* __restrict__ hp) {
  int id   = blockIdx.x * 256 + threadIdx.x;   // [0, 16*128*64)
  int lane = id & 63;
  int ks   = (id >> 6) & 127;
  int bblk = id >> 13;
  int b = bblk * 32 + (lane & 31);
  int k = ks * 16 + (lane >> 5) * 8;
  const float4v* src = (const float4v*)(hsrc + (size_t)b * HID + k);
  float4v a = src[0], c = src[1];
  half8 v;
  v[0]=(_Float16)a[0]; v[1]=(_Float16)a[1]; v[2]=(_Float16)a[2]; v[3]=(_Float16)a[3];
  v[4]=(_Float16)c[0]; v[5]=(_Float16)c[1]; v[6]=(_Float16)c[2]; v[7]=(_Float16)c[3];
  hp[id] = v;
}

__global__ void bias_k(const float* __restrict__ bih, const float* __restrict__ bhh,
                       float* __restrict__ bias) {
  int i = blockIdx.x * 256 + threadIdx.x;
  if (i < HID) bias[i] = bih[i] + bhh[i];
}

__global__ void outinit_k(float* __restrict__ out, const float* __restrict__ bout) {
  int i = blockIdx.x * 256 + threadIdx.x;      // grid covers T*B exactly
  out[i] = bout[0];
}

// Canonicalize tf_mask (int64 0/1, int32 0/1, or 1-byte bool) -> int[256].
__global__ void tf_expand_k(const int* __restrict__ tf, int* __restrict__ tfc) {
  __shared__ int fmt;   // 0=bytes, 1=int32, 2=int64
  if (threadIdx.x == 0) {
    const unsigned* u = (const unsigned*)tf;
    int all01 = 1;
    for (int i = 0; i < 32; ++i) if (u[i] > 1u) all01 = 0;
    if (all01) {
      int odd0 = 1;
      for (int i = 1; i < 32; i += 2) if (u[i] != 0u) odd0 = 0;
      fmt = odd0 ? 2 : 1;
    } else {
      fmt = 0;
    }
  }
  __syncthreads();
  int i = threadIdx.x;
  int v;
  if (fmt == 2)      v = tf[2 * i];
  else if (fmt == 1) v = tf[i];
  else               v = (int)((const unsigned char*)tf)[i];
  tfc[i] = v ? 1 : 0;
}

// ---- one recurrence step ----
// 256 blocks x 512 threads (8 waves). bid: n = bid&31 (XCD = n%8 -> 1MB W slice +
// h L2-local), m = bid>>5. Block (m,n): rows m*64..+64, cols n*64..+64.
// Wave w = k-eighth (ks w*16..+16). No redundant fragment reads.
__global__ __launch_bounds__(512) void step_k(
    const float* __restrict__ x0,   const float* __restrict__ tgt,
    const int*   __restrict__ tfc,  const float* __restrict__ wih,
    const float* __restrict__ wout, const float* __restrict__ bias,
    const half8* __restrict__ wp,   const half8* __restrict__ hr,
    half8* __restrict__ hw,         float* __restrict__ out, int t) {
  __shared__ float part[4][64][68];   // k-partial pre-activations (two-phase)
  __shared__ float hs[64][68];        // tanh'd h tile (f32)
  __shared__ float xs[64];
  __shared__ float ypart[8][64];
  __shared__ float wih_s[64], wout_s[64], bias_s[64];

  const int bid = blockIdx.x;
  const int n = bid & 31;
  const int m = bid >> 5;
  const int tid = threadIdx.x;
  const int w = tid >> 6;     // wave = k-eighth, 0..7
  const int l = tid & 63;
  const int hi = l >> 5;
  const int c = l & 31;

  if (tid < 64) {
    int j = n * 64 + tid;
    wih_s[tid]  = wih[j];
    wout_s[tid] = wout[j];
    bias_s[tid] = bias[j];
    int b = m * 64 + tid;
    float x;
    if (t == 0) x = x0[b];
    else        x = tfc[t - 1] ? tgt[(t - 1) * BATCH + b] : out[(t - 1) * BATCH + b];
    xs[tid] = x;
  }

  f32x16 acc00 = zero16(), acc01 = zero16(), acc10 = zero16(), acc11 = zero16();
  {
    const half8* a0p = hr + ((size_t)(2 * m + 0) * KS + w * 16) * 64 + l;
    const half8* a1p = hr + ((size_t)(2 * m + 1) * KS + w * 16) * 64 + l;
    const half8* b0p = wp + ((size_t)(2 * n + 0) * KS + w * 16) * 64 + l;
    const half8* b1p = wp + ((size_t)(2 * n + 1) * KS + w * 16) * 64 + l;
#pragma unroll
    for (int i = 0; i < 16; ++i) {
      half8 a0 = a0p[i * 64];
      half8 a1 = a1p[i * 64];
      half8 b0 = b0p[i * 64];
      half8 b1 = b1p[i * 64];
      acc00 = __builtin_amdgcn_mfma_f32_32x32x16_f16(a0, b0, acc00, 0, 0, 0);
      acc01 = __builtin_amdgcn_mfma_f32_32x32x16_f16(a0, b1, acc01, 0, 0, 0);
      acc10 = __builtin_amdgcn_mfma_f32_32x32x16_f16(a1, b0, acc10, 0, 0, 0);
      acc11 = __builtin_amdgcn_mfma_f32_32x32x16_f16(a1, b1, acc11, 0, 0, 0);
    }
  }

  // C/D layout (m74/m101): col = lane&31, row = (reg&3) + 8*(reg>>2) + 4*(lane>>5)
  // Phase 1: waves 0-3 write their partials.
  if (w < 4) {
#pragma unroll
    for (int r = 0; r < 16; ++r) {
      int row0 = (r & 3) + 8 * (r >> 2) + 4 * hi;
      part[w][row0     ][c     ] = acc00[r];
      part[w][row0     ][c + 32] = acc01[r];
      part[w][row0 + 32][c     ] = acc10[r];
      part[w][row0 + 32][c + 32] = acc11[r];
    }
  }
  __syncthreads();
  // Phase 2: waves 4-7 accumulate in place (same lane pattern -> no races).
  if (w >= 4) {
    int ww = w - 4;
#pragma unroll
    for (int r = 0; r < 16; ++r) {
      int row0 = (r & 3) + 8 * (r >> 2) + 4 * hi;
      part[ww][row0     ][c     ] += acc00[r];
      part[ww][row0     ][c + 32] += acc01[r];
      part[ww][row0 + 32][c     ] += acc10[r];
      part[ww][row0 + 32][c + 32] += acc11[r];
    }
  }
  __syncthreads();

  // Phase 3: octant combine (8 waves x 8 regs), + bias + rank-1 input, tanh.
  {
    int mb = w & 1, nb = (w >> 1) & 1, rh = w >> 2;
#pragma unroll
    for (int r = 0; r < 8; ++r) {
      int rr = rh * 8 + r;
      int row = mb * 32 + (rr & 3) + 8 * (rr >> 2) + 4 * hi;
      int col = nb * 32 + c;
      float s = part[0][row][col] + part[1][row][col]
              + part[2][row][col] + part[3][row][col];
      s += bias_s[col] + xs[row] * wih_s[col];
      hs[row][col] = tanhf(s);
    }
  }
  __syncthreads();

  // Repack h_t to A-fragment layout (fp16) + per-group y partials. 512 threads:
  // thread = (row = tid&63, g = tid>>6): cols g*8..+8 -> frag ks = n*4 + (g>>1),
  // lane = (g&1)*32 + (row&31).
  {
    int row = tid & 63;
    int g   = tid >> 6;
    float hv[8];
    float4v v0 = *(const float4v*)&hs[row][g * 8];
    float4v v1 = *(const float4v*)&hs[row][g * 8 + 4];
    hv[0]=v0[0]; hv[1]=v0[1]; hv[2]=v0[2]; hv[3]=v0[3];
    hv[4]=v1[0]; hv[5]=v1[1]; hv[6]=v1[2]; hv[7]=v1[3];

    float yp = 0.0f;
#pragma unroll
    for (int e = 0; e < 8; ++e) yp += hv[e] * wout_s[g * 8 + e];
    ypart[g][row] = yp;

    half8 f;
#pragma unroll
    for (int e = 0; e < 8; ++e) f[e] = (_Float16)hv[e];
    int bblk = 2 * m + (row >> 5);
    int ksg  = n * 4 + (g >> 1);
    int lane = (g & 1) * 32 + (row & 31);
    hw[((size_t)bblk * KS + ksg) * 64 + lane] = f;
  }
  __syncthreads();

  if (tid < 64) {
    float y = ypart[0][tid] + ypart[1][tid] + ypart[2][tid] + ypart[3][tid]
            + ypart[4][tid] + ypart[5][tid] + ypart[6][tid] + ypart[7][tid];
    atomicAdd(out + (size_t)t * BATCH + m * 64 + tid, y);
  }
}

extern "C" void kernel_launch(void* const* d_in, const int* in_sizes, int n_in,
                              void* d_out, int out_size, void* d_ws, size_t ws_size,
                              hipStream_t stream) {
  (void)in_sizes; (void)n_in; (void)out_size; (void)ws_size;
  const float* x0   = (const float*)d_in[0];
  const float* hid  = (const float*)d_in[1];
  const float* tgt  = (const float*)d_in[2];
  const float* wih  = (const float*)d_in[3];
  const float* bih  = (const float*)d_in[4];
  const float* whh  = (const float*)d_in[5];
  const float* bhh  = (const float*)d_in[6];
  const float* wout = (const float*)d_in[7];
  const float* bout = (const float*)d_in[8];
  const int*   tf   = (const int*)d_in[9];
  float* out = (float*)d_out;

  char* ws = (char*)d_ws;
  half8* wp   = (half8*)ws;                        // 8 MB packed W_hh fp16
  half8* h0   = (half8*)(ws + (8u  << 20));        // 2 MB packed h (ping)
  half8* h1   = (half8*)(ws + (10u << 20));        // 2 MB packed h (pong)
  float* bias = (float*)(ws + (12u << 20));        // 8 KB b_ih + b_hh
  int*   tfc  = (int*)  (ws + (12u << 20) + 8192); // 1 KB canonical tf

  pack_whh_k <<<2048, 256, 0, stream>>>(whh, wp);
  pack_h_k   <<<512,  256, 0, stream>>>(hid, h0);
  bias_k     <<<8,    256, 0, stream>>>(bih, bhh, bias);
  outinit_k  <<<512,  256, 0, stream>>>(out, bout);
  tf_expand_k<<<1,    256, 0, stream>>>(tf, tfc);

  for (int t = 0; t < T_STEPS; ++t) {
    const half8* hr = (t & 1) ? h1 : h0;
    half8*       hv = (t & 1) ? h0 : h1;
    step_k<<<256, 512, 0, stream>>>(x0, tgt, tfc, wih, wout, bias, wp, hr, hv, out, t);
  }
}